// Round 11
// baseline (1312.135 us; speedup 1.0000x reference)
//
#include <hip/hip_runtime.h>

// Viterbi decode (CRF): B=128, T=4096, L=64.
// Outputs: score[B] (f32), path[B][T] (written as float labels).
constexpr int kB = 128;
constexpr int kT = 4096;
constexpr int kL = 64;
constexpr int kSeg = 64;     // number of backtrace segments
constexpr int kSegLen = 64;  // rows per segment (last segment has 63)
constexpr float kNeg = -10000.0f;

typedef float f32x2 __attribute__((ext_vector_type(2)));
typedef float f32x4 __attribute__((ext_vector_type(4)));

#if __has_builtin(__builtin_amdgcn_permlane16_swap)
#define HAS_PL16 1
#else
#define HAS_PL16 0
#endif

// ---------------- K1A forward: all-VALU broadcast, asm-fused DPP ------------
// Lane i owns label i; delta in ONE register. Bases (4 regs; per 16-lane row
// they hold 4 distinct 16-label chunks) built by tier A (permlane32_swap +
// 2x permlane16_swap, zero DS) or tier B (permlane32_swap + 2x ds_swizzle).
// The 16-chunk reduction is ONE pure asm block: s_nop 3 hazard guard, then
// 16x v_add_f32_dpp row_ror:k FUSED (builtin update_dpp+add was emitting
// mov_dpp+add pairs -> ~217 instr/step measured R10), interleaved v_max3.
// trb gathered at init in PROBED order; step t=1 bitwise-verified vs the
// exact LDS step; any mismatch -> exact LDS loop. Earlyclobber outputs.

template <int K>
__device__ __forceinline__ int rotidx(int v) {
  // row_ror:K  (DPP ctrl 0x120|K), all rows/banks, bound_ctrl on
  return __builtin_amdgcn_update_dpp(0, v, 0x120 | K, 0xF, 0xF, true);
}

__device__ __forceinline__ float reduce16_asm(float base, const float (&tr)[16]) {
  float acc, u, v;
  asm("s_nop 3\n\t"
      "v_add_f32 %0, %3, %4\n\t"
      "v_add_f32_dpp %1, %3, %5 row_ror:1 row_mask:0xf bank_mask:0xf\n\t"
      "v_add_f32_dpp %2, %3, %6 row_ror:2 row_mask:0xf bank_mask:0xf\n\t"
      "v_max3_f32 %0, %0, %1, %2\n\t"
      "v_add_f32_dpp %1, %3, %7 row_ror:3 row_mask:0xf bank_mask:0xf\n\t"
      "v_add_f32_dpp %2, %3, %8 row_ror:4 row_mask:0xf bank_mask:0xf\n\t"
      "v_max3_f32 %0, %0, %1, %2\n\t"
      "v_add_f32_dpp %1, %3, %9 row_ror:5 row_mask:0xf bank_mask:0xf\n\t"
      "v_add_f32_dpp %2, %3, %10 row_ror:6 row_mask:0xf bank_mask:0xf\n\t"
      "v_max3_f32 %0, %0, %1, %2\n\t"
      "v_add_f32_dpp %1, %3, %11 row_ror:7 row_mask:0xf bank_mask:0xf\n\t"
      "v_add_f32_dpp %2, %3, %12 row_ror:8 row_mask:0xf bank_mask:0xf\n\t"
      "v_max3_f32 %0, %0, %1, %2\n\t"
      "v_add_f32_dpp %1, %3, %13 row_ror:9 row_mask:0xf bank_mask:0xf\n\t"
      "v_add_f32_dpp %2, %3, %14 row_ror:10 row_mask:0xf bank_mask:0xf\n\t"
      "v_max3_f32 %0, %0, %1, %2\n\t"
      "v_add_f32_dpp %1, %3, %15 row_ror:11 row_mask:0xf bank_mask:0xf\n\t"
      "v_add_f32_dpp %2, %3, %16 row_ror:12 row_mask:0xf bank_mask:0xf\n\t"
      "v_max3_f32 %0, %0, %1, %2\n\t"
      "v_add_f32_dpp %1, %3, %17 row_ror:13 row_mask:0xf bank_mask:0xf\n\t"
      "v_add_f32_dpp %2, %3, %18 row_ror:14 row_mask:0xf bank_mask:0xf\n\t"
      "v_max3_f32 %0, %0, %1, %2\n\t"
      "v_add_f32_dpp %1, %3, %19 row_ror:15 row_mask:0xf bank_mask:0xf\n\t"
      "v_max_f32 %0, %0, %1"
      : "=&v"(acc), "=&v"(u), "=&v"(v)
      : "v"(base), "v"(tr[0]), "v"(tr[1]), "v"(tr[2]), "v"(tr[3]), "v"(tr[4]),
        "v"(tr[5]), "v"(tr[6]), "v"(tr[7]), "v"(tr[8]), "v"(tr[9]), "v"(tr[10]),
        "v"(tr[11]), "v"(tr[12]), "v"(tr[13]), "v"(tr[14]), "v"(tr[15]));
  return acc;
}

#if HAS_PL16
__device__ __forceinline__ float step_planeA(const float (&trb)[4][16], float d, float f) {
  auto w = __builtin_amdgcn_permlane32_swap(__float_as_uint(d), __float_as_uint(d),
                                            false, false);
  auto wa = __builtin_amdgcn_permlane16_swap((unsigned)w[0], (unsigned)w[0], false, false);
  auto wb = __builtin_amdgcn_permlane16_swap((unsigned)w[1], (unsigned)w[1], false, false);
  float acc0 = reduce16_asm(__uint_as_float(wa[0]), trb[0]);
  float acc1 = reduce16_asm(__uint_as_float(wa[1]), trb[1]);
  float acc2 = reduce16_asm(__uint_as_float(wb[0]), trb[2]);
  float acc3 = reduce16_asm(__uint_as_float(wb[1]), trb[3]);
  return fmaxf(fmaxf(acc0, acc1), fmaxf(acc2, acc3)) + f;
}
#endif

__device__ __forceinline__ float step_planeB(const float (&trb)[4][16], float d, float f) {
  auto w32 = __builtin_amdgcn_permlane32_swap(__float_as_uint(d), __float_as_uint(d),
                                              false, false);
  int a = (int)w32[0], bb = (int)w32[1];
  int sa = __builtin_amdgcn_ds_swizzle(a, 0x401F);   // lane^16 (issued early)
  int sb = __builtin_amdgcn_ds_swizzle(bb, 0x401F);
  float acc0 = reduce16_asm(__int_as_float(a), trb[0]);
  float acc1 = reduce16_asm(__int_as_float(bb), trb[1]);
  float acc2 = reduce16_asm(__int_as_float(sa), trb[2]);
  float acc3 = reduce16_asm(__int_as_float(sb), trb[3]);
  return fmaxf(fmaxf(acc0, acc1), fmaxf(acc2, acc3)) + f;
}

// ---- exact step (R7 structure; verify reference + tier-C fallback) ---------
__device__ __forceinline__ float step_lds(const f32x2 (&tr2)[kL / 2], float* dl,
                                          const f32x4* dl4, int i, float d, float f) {
  asm volatile("" ::: "memory");
  dl[i] = d;
  asm volatile("" ::: "memory");
  f32x4 v[16];
#pragma unroll
  for (int q = 0; q < 16; ++q) v[q] = dl4[q];
  __builtin_amdgcn_sched_barrier(0);
  f32x2 mm[16];
#pragma unroll
  for (int q = 0; q < 16; ++q) {
    f32x2 p = tr2[2 * q] + v[q].lo;
    f32x2 r = tr2[2 * q + 1] + v[q].hi;
    mm[q] = __builtin_elementwise_max(p, r);
  }
#pragma unroll
  for (int s = 8; s; s >>= 1)
    for (int q = 0; q < s; ++q) mm[q] = __builtin_elementwise_max(mm[q], mm[q + s]);
  return fmaxf(mm[0].x, mm[0].y) + f;
}

__global__ __launch_bounds__(64, 1) void fwd_delta(const float* __restrict__ feats,
                                                   const float* __restrict__ trans,
                                                   float* __restrict__ delta) {
  const int i = threadIdx.x;
  const int b = blockIdx.x;
  const size_t kBL = (size_t)kB * kL;
  __shared__ float dl[kL];
  const f32x4* dl4 = reinterpret_cast<const f32x4*>(dl);

  float trb[4][16];
  int mode = 0;  // 0=LDS, 1=planeA, 2=planeB

#define TRY_ARRANGEMENT(b0, b1, b2, b3, MODE)                                   \
  if (mode == 0) {                                                              \
    int baseq[4] = {b0, b1, b2, b3};                                            \
    unsigned long long cov = 0;                                                 \
    _Pragma("unroll") for (int c = 0; c < 4; ++c) {                             \
      int s0 = baseq[c] & 63;                                                   \
      cov |= 1ull << s0;                                                        \
      trb[c][0] = trans[i * kL + s0];                                           \
      int s;                                                                    \
      s = rotidx<1>(baseq[c]) & 63;  cov |= 1ull << s; trb[c][1]  = trans[i * kL + s]; \
      s = rotidx<2>(baseq[c]) & 63;  cov |= 1ull << s; trb[c][2]  = trans[i * kL + s]; \
      s = rotidx<3>(baseq[c]) & 63;  cov |= 1ull << s; trb[c][3]  = trans[i * kL + s]; \
      s = rotidx<4>(baseq[c]) & 63;  cov |= 1ull << s; trb[c][4]  = trans[i * kL + s]; \
      s = rotidx<5>(baseq[c]) & 63;  cov |= 1ull << s; trb[c][5]  = trans[i * kL + s]; \
      s = rotidx<6>(baseq[c]) & 63;  cov |= 1ull << s; trb[c][6]  = trans[i * kL + s]; \
      s = rotidx<7>(baseq[c]) & 63;  cov |= 1ull << s; trb[c][7]  = trans[i * kL + s]; \
      s = rotidx<8>(baseq[c]) & 63;  cov |= 1ull << s; trb[c][8]  = trans[i * kL + s]; \
      s = rotidx<9>(baseq[c]) & 63;  cov |= 1ull << s; trb[c][9]  = trans[i * kL + s]; \
      s = rotidx<10>(baseq[c]) & 63; cov |= 1ull << s; trb[c][10] = trans[i * kL + s]; \
      s = rotidx<11>(baseq[c]) & 63; cov |= 1ull << s; trb[c][11] = trans[i * kL + s]; \
      s = rotidx<12>(baseq[c]) & 63; cov |= 1ull << s; trb[c][12] = trans[i * kL + s]; \
      s = rotidx<13>(baseq[c]) & 63; cov |= 1ull << s; trb[c][13] = trans[i * kL + s]; \
      s = rotidx<14>(baseq[c]) & 63; cov |= 1ull << s; trb[c][14] = trans[i * kL + s]; \
      s = rotidx<15>(baseq[c]) & 63; cov |= 1ull << s; trb[c][15] = trans[i * kL + s]; \
    }                                                                           \
    if (__all(cov == 0xFFFFFFFFFFFFFFFFull)) mode = MODE;                       \
  }

  // probe with lane indices, same permute pipeline as the step functions
  auto wp = __builtin_amdgcn_permlane32_swap((unsigned)i, (unsigned)i, false, false);
#if HAS_PL16
  {
    auto wpa = __builtin_amdgcn_permlane16_swap((unsigned)wp[0], (unsigned)wp[0],
                                                false, false);
    auto wpb = __builtin_amdgcn_permlane16_swap((unsigned)wp[1], (unsigned)wp[1],
                                                false, false);
    TRY_ARRANGEMENT((int)wpa[0], (int)wpa[1], (int)wpb[0], (int)wpb[1], 1)
  }
#endif
  {
    int sa = __builtin_amdgcn_ds_swizzle((int)wp[0], 0x401F);
    int sb = __builtin_amdgcn_ds_swizzle((int)wp[1], 0x401F);
    TRY_ARRANGEMENT((int)wp[0], (int)wp[1], sa, sb, 2)
  }
#undef TRY_ARRANGEMENT

  // transitions row for verify + tier-C (dead in plane loops)
  f32x2 tr2[kL / 2];
#pragma unroll
  for (int k = 0; k < kL; k += 4) {
    float4 v = *reinterpret_cast<const float4*>(trans + i * kL + k);
    tr2[k / 2].x = v.x; tr2[k / 2].y = v.y;
    tr2[k / 2 + 1].x = v.z; tr2[k / 2 + 1].y = v.w;
  }

  float d = (i == 62) ? 0.0f : kNeg;
  float* drow = delta + (size_t)b * kL + i;  // layout [T][B][L]
  *drow = d;
  drow += kBL;
  const float* fp = feats + (size_t)b * kT * kL + i;
  float fA = fp[64 * 1], fB = fp[64 * 2], fC = fp[64 * 3], fD = fp[64 * 4];

  // ---- verify step t=1 bitwise against the exact LDS step ----
  float dP;
#if HAS_PL16
  if (mode == 1) dP = step_planeA(trb, d, fA); else
#endif
  if (mode == 2) dP = step_planeB(trb, d, fA);
  else dP = 0.0f;
  float dE = step_lds(tr2, dl, dl4, i, d, fA);
  if (mode != 0 && !__all(__float_as_int(dP) == __float_as_int(dE))) mode = 0;
  d = dE;
  *drow = d;
  drow += kBL;
  fA = fp[64 * 5];
  const float* pf = fp + 64 * 6;

#if HAS_PL16
  if (mode == 1) {
    for (int it = 0; it < 1022; ++it) {  // steps t=2..4089
      d = step_planeA(trb, d, fB); *drow = d; drow += kBL; fB = pf[0];
      d = step_planeA(trb, d, fC); *drow = d; drow += kBL; fC = pf[64];
      d = step_planeA(trb, d, fD); *drow = d; drow += kBL; fD = pf[128];
      d = step_planeA(trb, d, fA); *drow = d; drow += kBL; fA = pf[192];
      pf += 256;
    }
    float g0 = pf[0], g1 = pf[64];  // t=4094, 4095
    d = step_planeA(trb, d, fB); *drow = d; drow += kBL;
    d = step_planeA(trb, d, fC); *drow = d; drow += kBL;
    d = step_planeA(trb, d, fD); *drow = d; drow += kBL;
    d = step_planeA(trb, d, fA); *drow = d; drow += kBL;
    d = step_planeA(trb, d, g0); *drow = d; drow += kBL;
    d = step_planeA(trb, d, g1); *drow = d;
    return;
  }
#endif
  if (mode == 2) {
    for (int it = 0; it < 1022; ++it) {
      d = step_planeB(trb, d, fB); *drow = d; drow += kBL; fB = pf[0];
      d = step_planeB(trb, d, fC); *drow = d; drow += kBL; fC = pf[64];
      d = step_planeB(trb, d, fD); *drow = d; drow += kBL; fD = pf[128];
      d = step_planeB(trb, d, fA); *drow = d; drow += kBL; fA = pf[192];
      pf += 256;
    }
    float g0 = pf[0], g1 = pf[64];
    d = step_planeB(trb, d, fB); *drow = d; drow += kBL;
    d = step_planeB(trb, d, fC); *drow = d; drow += kBL;
    d = step_planeB(trb, d, fD); *drow = d; drow += kBL;
    d = step_planeB(trb, d, fA); *drow = d; drow += kBL;
    d = step_planeB(trb, d, g0); *drow = d; drow += kBL;
    d = step_planeB(trb, d, g1); *drow = d;
    return;
  }
  {
    for (int it = 0; it < 1022; ++it) {
      d = step_lds(tr2, dl, dl4, i, d, fB); *drow = d; drow += kBL; fB = pf[0];
      d = step_lds(tr2, dl, dl4, i, d, fC); *drow = d; drow += kBL; fC = pf[64];
      d = step_lds(tr2, dl, dl4, i, d, fD); *drow = d; drow += kBL; fD = pf[128];
      d = step_lds(tr2, dl, dl4, i, d, fA); *drow = d; drow += kBL; fA = pf[192];
      pf += 256;
    }
    float g0 = pf[0], g1 = pf[64];
    d = step_lds(tr2, dl, dl4, i, d, fB); *drow = d; drow += kBL;
    d = step_lds(tr2, dl, dl4, i, d, fC); *drow = d; drow += kBL;
    d = step_lds(tr2, dl, dl4, i, d, fD); *drow = d; drow += kBL;
    d = step_lds(tr2, dl, dl4, i, d, fA); *drow = d; drow += kBL;
    d = step_lds(tr2, dl, dl4, i, d, g0); *drow = d; drow += kBL;
    d = step_lds(tr2, dl, dl4, i, d, g1); *drow = d;
  }
}

// ---------------- K2: recompute backpointers from stored delta --------------
// row r = t*128 + b; delta layout [T][B][L] makes row base = delta + r*64.
__global__ __launch_bounds__(256) void psi_from_delta(const float* __restrict__ delta,
                                                      const float* __restrict__ trans,
                                                      unsigned char* __restrict__ psi) {
  const int lane = threadIdx.x & 63;
  const int w = __builtin_amdgcn_readfirstlane(blockIdx.x * 4 + (threadIdx.x >> 6));
  float tr[kL];
#pragma unroll
  for (int k = 0; k < kL; k += 4) {
    float4 v = *reinterpret_cast<const float4*>(trans + lane * kL + k);
    tr[k] = v.x; tr[k + 1] = v.y; tr[k + 2] = v.z; tr[k + 3] = v.w;
  }
  const int r0 = w * 8;  // 8 rows per wave; grid sized exactly
  for (int rr = 0; rr < 8; ++rr) {
    const int r = r0 + rr;
    const float4* row4 = reinterpret_cast<const float4*>(delta + (size_t)r * kL);
    float bA = -INFINITY, bBv = -INFINITY;
    int iA = 0, iB = 32;
#pragma unroll
    for (int q = 0; q < 8; ++q) {
      float4 dv = row4[q];
      float c; bool g;
      c = tr[4 * q + 0] + dv.x; g = c > bA; bA = g ? c : bA; iA = g ? 4 * q + 0 : iA;
      c = tr[4 * q + 1] + dv.y; g = c > bA; bA = g ? c : bA; iA = g ? 4 * q + 1 : iA;
      c = tr[4 * q + 2] + dv.z; g = c > bA; bA = g ? c : bA; iA = g ? 4 * q + 2 : iA;
      c = tr[4 * q + 3] + dv.w; g = c > bA; bA = g ? c : bA; iA = g ? 4 * q + 3 : iA;
    }
#pragma unroll
    for (int q = 8; q < 16; ++q) {
      float4 dv = row4[q];
      float c; bool g;
      c = tr[4 * q + 0] + dv.x; g = c > bBv; bBv = g ? c : bBv; iB = g ? 4 * q + 0 : iB;
      c = tr[4 * q + 1] + dv.y; g = c > bBv; bBv = g ? c : bBv; iB = g ? 4 * q + 1 : iB;
      c = tr[4 * q + 2] + dv.z; g = c > bBv; bBv = g ? c : bBv; iB = g ? 4 * q + 2 : iB;
      c = tr[4 * q + 3] + dv.w; g = c > bBv; bBv = g ? c : bBv; iB = g ? 4 * q + 3 : iB;
    }
    bool gm = bBv > bA;  // tie -> lower half (first occurrence)
    psi[(size_t)r * kL + lane] = (unsigned char)(gm ? iB : iA);
  }
}

// ---------------- K3: segment composition (in-place psi -> M) ----------------
__global__ __launch_bounds__(256) void seg_compose(unsigned char* psiM,
                                                   unsigned char* __restrict__ C) {
  const int lane = threadIdx.x & 63;
  const int w = blockIdx.x * 4 + (threadIdx.x >> 6);
  const int s = w >> 7;
  const int b = w & 127;
  const int tstart = s * kSegLen;
  const int tend = (tstart + kSegLen < kT) ? tstart + kSegLen : kT - 1;  // last seg: 4095
  const size_t stride = (size_t)kB * kL;
  size_t off = ((size_t)(tend - 1) * kB + b) * kL + lane;
  int m = lane;
  int v = psiM[off];
  for (int t = tend - 1; t > tstart; --t) {
    int vn = psiM[off - stride];          // prefetch next row
    m = __shfl(v, m, 64);                 // m = psi_row[m]
    psiM[off] = (unsigned char)m;         // M[t][b][e] = path[t] | hyp e
    v = vn;
    off -= stride;
  }
  m = __shfl(v, m, 64);
  psiM[off] = (unsigned char)m;
  C[((size_t)s * kB + b) * kL + lane] = (unsigned char)m;  // composed map
}

// ---------------- K4: score, last label, boundary-label scan ----------------
__global__ __launch_bounds__(64) void score_scan(const float* __restrict__ dfin,
                                                 const unsigned char* __restrict__ C,
                                                 int* __restrict__ E,
                                                 float* __restrict__ out) {
  const int b = blockIdx.x;
  const int i = threadIdx.x;
  float d = dfin[(size_t)b * kL + i];
  float m = d;
#pragma unroll
  for (int off = 32; off; off >>= 1) m = fmaxf(m, __shfl_xor(m, off, 64));
  unsigned long long msk = __ballot(d == m);
  int ll = __ffsll(msk) - 1;  // first (lowest) argmax lane
  if (i == 0) {
    out[b] = m;
    out[kB + (size_t)b * kT + (kT - 1)] = (float)ll;
    int lbl = ll;
    for (int s = kSeg - 1; s >= 0; --s) {
      E[s * kB + b] = lbl;                              // label at t_end(s)
      lbl = C[((size_t)s * kB + b) * kL + lbl];         // -> label at t_start(s)
    }
  }
}

// ---------------- K5: parallel path gather ----------------
__global__ __launch_bounds__(256) void path_fill(const unsigned char* __restrict__ M,
                                                 const int* __restrict__ E,
                                                 float* __restrict__ out) {
  const int n = blockIdx.x * 256 + threadIdx.x;  // n = b*4096 + t
  const int b = n >> 12;
  const int t = n & (kT - 1);
  if (t == kT - 1) return;  // written by score_scan
  const int e = E[(t >> 6) * kB + b];
  const unsigned char lab = M[((size_t)t * kB + b) * kL + e];
  out[kB + (size_t)b * kT + t] = (float)lab;
}

extern "C" void kernel_launch(void* const* d_in, const int* in_sizes, int n_in,
                              void* d_out, int out_size, void* d_ws, size_t ws_size,
                              hipStream_t stream) {
  const float* feats = (const float*)d_in[0];
  const float* trans = (const float*)d_in[1];
  float* out = (float*)d_out;
  char* ws = (char*)d_ws;

  const size_t deltaB = (size_t)kT * kB * kL * 4;   // 134,217,728
  const size_t psiB   = (size_t)kT * kB * kL;       //  33,554,432
  const size_t CBy    = (size_t)kSeg * kB * kL;     //     524,288

  float* delta = (float*)ws;
  unsigned char* psi = (unsigned char*)(ws + deltaB);
  unsigned char* C = (unsigned char*)(ws + deltaB + psiB);
  int* E = (int*)(ws + deltaB + psiB + CBy);
  hipLaunchKernelGGL(fwd_delta, dim3(kB), dim3(64), 0, stream, feats, trans, delta);
  hipLaunchKernelGGL(psi_from_delta, dim3(16380), dim3(256), 0, stream, delta, trans, psi);
  hipLaunchKernelGGL(seg_compose, dim3(2048), dim3(256), 0, stream, psi, C);
  hipLaunchKernelGGL(score_scan, dim3(kB), dim3(64), 0, stream,
                     delta + (size_t)(kT - 1) * kB * kL, C, E, out);
  hipLaunchKernelGGL(path_fill, dim3(2048), dim3(256), 0, stream, psi, E, out);
}